// Round 13
// baseline (147.746 us; speedup 1.0000x reference)
//
#include <hip/hip_runtime.h>
#include <hip/hip_bf16.h>

typedef _Float16 f16_t;
typedef __attribute__((ext_vector_type(8))) _Float16 f16x8;
typedef __attribute__((ext_vector_type(4))) float f32x4;

#define LFENCE() asm volatile("" ::: "memory")

__device__ __forceinline__ f16x8 cvt8(const float* p) {
  float4 v0 = *(const float4*)p;
  float4 v1 = *(const float4*)(p + 4);
  f16x8 a;
  a[0] = (f16_t)v0.x; a[1] = (f16_t)v0.y; a[2] = (f16_t)v0.z; a[3] = (f16_t)v0.w;
  a[4] = (f16_t)v1.x; a[5] = (f16_t)v1.y; a[6] = (f16_t)v1.z; a[7] = (f16_t)v1.w;
  return a;
}

// ---------------------------------------------------------------------------
// prep (verified r6-r12): blocks 0..10 transpose+f16 weights
//   slots 0..7 = {wq_s,wk_s,wv_s,wq_c,wk_c,wv_c,wo_s,wo_c}^T [col][k],
//   8..10 = WgT [128 col][384 k]. Blocks 11,12: W2'=(WoS@Wg2)^T, W3'=(WoC@Wg3)^T.
// Block 13: bg' = bg + bos@Wg2 + boc@Wg3.
// ---------------------------------------------------------------------------
__global__ __launch_bounds__(256) void prep_kernel(
    const float* wq_s, const float* wk_s, const float* wv_s,
    const float* wq_c, const float* wk_c, const float* wv_c,
    const float* wo_s, const float* wo_c, const float* wg,
    const float* bos, const float* boc, const float* bgin,
    f16_t* WT, float* bgp)
{
  const int b = blockIdx.x;
  const int tid = threadIdx.x;
  if (b < 11) {
    __shared__ float t[128][129];
    const float* src; f16_t* dst; int ostride;
    switch (b) {
      case 0: src = wq_s; break; case 1: src = wk_s; break;
      case 2: src = wv_s; break; case 3: src = wq_c; break;
      case 4: src = wk_c; break; case 5: src = wv_c; break;
      case 6: src = wo_s; break; case 7: src = wo_c; break;
      default: src = wg + (size_t)(b - 8) * 16384; break;
    }
    if (b < 8) { dst = WT + (size_t)b * 16384; ostride = 128; }
    else       { dst = WT + 8 * 16384 + (b - 8) * 128; ostride = 384; }
#pragma unroll
    for (int i = 0; i < 64; ++i) {
      const int idx = tid + i * 256;
      t[idx & 127][idx >> 7] = src[idx];
    }
    __syncthreads();
#pragma unroll
    for (int i = 0; i < 64; ++i) {
      const int idx = tid + i * 256;
      const int c = idx >> 7, r = idx & 127;
      dst[(size_t)c * ostride + r] = (f16_t)t[c][r];
    }
  } else if (b < 13) {
    const int matsel = b - 11;
    const float* wo = matsel ? wo_c : wo_s;
    const int joff = 128 + matsel * 128;
    f16_t* dst = WT + (size_t)(11 + matsel) * 16384;
    const int wv = tid >> 6, ln = tid & 63, l15 = ln & 15, g = ln >> 4;
    f32x4 acc[2][8];
#pragma unroll
    for (int mm = 0; mm < 2; ++mm)
#pragma unroll
      for (int nt = 0; nt < 8; ++nt) acc[mm][nt] = (f32x4){0.f, 0.f, 0.f, 0.f};
#pragma unroll
    for (int kt = 0; kt < 4; ++kt) {
      f16x8 a[2];
#pragma unroll
      for (int mm = 0; mm < 2; ++mm) {
        const int crow = wv * 32 + mm * 16 + l15;
#pragma unroll
        for (int jj = 0; jj < 8; ++jj)
          a[mm][jj] = (f16_t)wg[(size_t)(joff + kt * 32 + g * 8 + jj) * 128 + crow];
      }
#pragma unroll
      for (int nt = 0; nt < 8; ++nt) {
        f16x8 bf = cvt8(wo + (size_t)(nt * 16 + l15) * 128 + kt * 32 + g * 8);
        acc[0][nt] = __builtin_amdgcn_mfma_f32_16x16x32_f16(a[0], bf, acc[0][nt], 0, 0, 0);
        acc[1][nt] = __builtin_amdgcn_mfma_f32_16x16x32_f16(a[1], bf, acc[1][nt], 0, 0, 0);
      }
    }
#pragma unroll
    for (int mm = 0; mm < 2; ++mm)
#pragma unroll
      for (int nt = 0; nt < 8; ++nt)
#pragma unroll
        for (int r = 0; r < 4; ++r) {
          const int c = wv * 32 + mm * 16 + g * 4 + r;
          dst[(size_t)c * 128 + nt * 16 + l15] = (f16_t)acc[mm][nt][r];
        }
  } else {
    if (tid < 128) {
      float acc = bgin[tid];
      for (int j = 0; j < 128; ++j)
        acc += bos[j] * wg[(size_t)(128 + j) * 128 + tid] +
               boc[j] * wg[(size_t)(256 + j) * 128 + tid];
      bgp[tid] = acc;
    }
  }
}

// ---------------------------------------------------------------------------
// Branch+headgroup attention: grid 2048 = hg(4) x branch(2) x batch(256);
// 512 thr = 8 waves; LDS ~34KB -> 4 blocks/CU = 32 waves/CU (8/SIMD).
// Block owns 2 heads (weight cols hg*32..+32). Wave rg owns q-rows rg*16..+16.
// Kb: [128 key][80B] (stride-80 = bank-uniform b128 reads); Vt: [32 d][256B]
// XOR-swizzled; scr: per-wave 1280B (Q-transpose, then P). 1 barrier.
// Attention math verbatim r12 (chunked unnormalized P, SHIFT=4, invq shfl).
// ---------------------------------------------------------------------------
__global__ __launch_bounds__(512) void battn2_kernel(
    const float* __restrict__ Xs, const float* __restrict__ Xc,
    const int* __restrict__ adj, const int* __restrict__ mask_s,
    const int* __restrict__ mask_c, const f16_t* __restrict__ WT,
    const float* __restrict__ bq_s, const float* __restrict__ bk_s,
    const float* __restrict__ bv_s, const float* __restrict__ bq_c,
    const float* __restrict__ bk_c, const float* __restrict__ bv_c,
    f16_t* __restrict__ att_s, f16_t* __restrict__ att_c)
{
  __shared__ __align__(16) char Kb[128 * 80];
  __shared__ __align__(16) char Vtb[32 * 256];
  __shared__ __align__(16) char WS[8 * 1280];

  const int bid = blockIdx.x;
  const int bb = bid & 255;
  const bool self = ((bid >> 8) & 1) == 0;
  const int hg = bid >> 9;            // head group 0..3 (2 heads each)
  const int colbase = hg * 32;
  const int tid = threadIdx.x;
  const int rg = tid >> 6, ln = tid & 63, l15 = ln & 15, g = ln >> 4;
  const int arow = rg * 16 + l15;
  char* scr = WS + rg * 1280;

  const f16_t* WQ = WT + (size_t)(self ? 0 : 3) * 16384;
  const f16_t* WK = WT + (size_t)(self ? 1 : 4) * 16384;
  const f16_t* WV = WT + (size_t)(self ? 2 : 5) * 16384;
  const float* bqv = self ? bq_s : bq_c;
  const float* bkv = self ? bk_s : bk_c;
  const float* bvv = self ? bv_s : bv_c;
  const float* XK  = self ? Xs : Xc;
  const int* mask  = self ? mask_s : mask_c;
  f16_t* ATT = self ? att_s : att_c;

  // masks via per-wave ballots (regs)
  unsigned mw[4];
  {
    unsigned long long m0 = __ballot(mask[bb * 128 + ln] != 0);
    unsigned long long m1 = __ballot(mask[bb * 128 + 64 + ln] != 0);
    mw[0] = (unsigned)m0; mw[1] = (unsigned)(m0 >> 32);
    mw[2] = (unsigned)m1; mw[3] = (unsigned)(m1 >> 32);
  }
  // adj bits -> regs (r12-proven): lane ln loads word w=ln>>4 of row rg*16+(ln&15)
  unsigned aw[4];
  if (self) {
    const int row = rg * 16 + (ln & 15);
    const int w = ln >> 4;
    const int4* ap = (const int4*)(adj + ((size_t)bb * 128 + row) * 128 + w * 32);
    unsigned word = 0;
#pragma unroll
    for (int i = 0; i < 8; ++i) {
      int4 a = ap[i];
      word |= ((a.x != 0 ? 1u : 0u) | (a.y != 0 ? 2u : 0u) |
               (a.z != 0 ? 4u : 0u) | (a.w != 0 ? 8u : 0u)) << (i * 4);
    }
#pragma unroll
    for (int w2 = 0; w2 < 4; ++w2)
      aw[w2] = (unsigned)__shfl((int)word, w2 * 16 + l15) & mw[w2];
  } else {
#pragma unroll
    for (int w2 = 0; w2 < 4; ++w2) aw[w2] = mw[w2];
  }

  // ---- ph1: K (2 heads) -> Kb, V^T -> Vtb, Q -> bq[2] regs ----
  f16x8 bq[2];
  {
    f16x8 afrK[4];
#pragma unroll
    for (int kt = 0; kt < 4; ++kt)
      afrK[kt] = cvt8(XK + (size_t)bb * 16384 + arow * 128 + kt * 32 + g * 8);

    // K-proj: nt=0,1 -> Kb[row][lcol], stride 80B, no XOR
    {
      f32x4 acc[2];
      acc[0] = (f32x4){0.f, 0.f, 0.f, 0.f};
      acc[1] = (f32x4){0.f, 0.f, 0.f, 0.f};
#pragma unroll
      for (int nt = 0; nt < 2; ++nt)
#pragma unroll
        for (int kt = 0; kt < 4; ++kt) {
          f16x8 b = *(const f16x8*)(WK + (size_t)(colbase + nt * 16 + l15) * 128 + kt * 32 + g * 8);
          acc[nt] = __builtin_amdgcn_mfma_f32_16x16x32_f16(afrK[kt], b, acc[nt], 0, 0, 0);
        }
#pragma unroll
      for (int nt = 0; nt < 2; ++nt) {
        const int lcol = nt * 16 + l15;
        const float bv = bkv[colbase + lcol];
#pragma unroll
        for (int r = 0; r < 4; ++r) {
          const int row = rg * 16 + g * 4 + r;
          *(f16_t*)(Kb + row * 80 + lcol * 2) = (f16_t)(acc[nt][r] + bv);
        }
      }
    }
    // V-proj transposed: Vt[lcol][key], 256B stride, XOR (lcol&7)<<4
    {
      f32x4 acc[2];
      acc[0] = (f32x4){0.f, 0.f, 0.f, 0.f};
      acc[1] = (f32x4){0.f, 0.f, 0.f, 0.f};
#pragma unroll
      for (int nt = 0; nt < 2; ++nt)
#pragma unroll
        for (int kt = 0; kt < 4; ++kt) {
          f16x8 b = *(const f16x8*)(WV + (size_t)(colbase + nt * 16 + l15) * 128 + kt * 32 + g * 8);
          acc[nt] = __builtin_amdgcn_mfma_f32_16x16x32_f16(afrK[kt], b, acc[nt], 0, 0, 0);
        }
#pragma unroll
      for (int nt = 0; nt < 2; ++nt) {
        const int lcol = nt * 16 + l15;
        const float bv = bvv[colbase + lcol];
#pragma unroll
        for (int r = 0; r < 4; ++r) {
          const int row = rg * 16 + g * 4 + r;
          *(f16_t*)(Vtb + lcol * 256 + ((row * 2) ^ ((lcol & 7) << 4))) = (f16_t)(acc[nt][r] + bv);
        }
      }
    }
    // Q-proj -> scratch transpose -> bq[2] (r12-proven mapping, stride 80)
    {
      f16x8 afrQ[4];
      if (self) {
#pragma unroll
        for (int kt = 0; kt < 4; ++kt) afrQ[kt] = afrK[kt];
      } else {
#pragma unroll
        for (int kt = 0; kt < 4; ++kt)
          afrQ[kt] = cvt8(Xs + (size_t)bb * 16384 + arow * 128 + kt * 32 + g * 8);
      }
      LFENCE();
      f32x4 acc[2];
      acc[0] = (f32x4){0.f, 0.f, 0.f, 0.f};
      acc[1] = (f32x4){0.f, 0.f, 0.f, 0.f};
#pragma unroll
      for (int nt = 0; nt < 2; ++nt)
#pragma unroll
        for (int kt = 0; kt < 4; ++kt) {
          f16x8 b = *(const f16x8*)(WQ + (size_t)(colbase + nt * 16 + l15) * 128 + kt * 32 + g * 8);
          acc[nt] = __builtin_amdgcn_mfma_f32_16x16x32_f16(afrQ[kt], b, acc[nt], 0, 0, 0);
        }
#pragma unroll
      for (int nt = 0; nt < 2; ++nt) {
        const int dloc = nt * 16 + l15;  // 0..31
        const float bv = bqv[colbase + dloc];
#pragma unroll
        for (int r = 0; r < 4; ++r) {
          const int qp = g * 4 + r;
          *(f16_t*)(scr + qp * 80 + dloc * 2) = (f16_t)(acc[nt][r] + bv);
        }
      }
      LFENCE();
#pragma unroll
      for (int h = 0; h < 2; ++h) {
        f16x8 z = {0, 0, 0, 0, 0, 0, 0, 0};
        bq[h] = (g < 2)
          ? *(const f16x8*)(scr + l15 * 80 + (h * 16 + g * 8) * 2)
          : z;
      }
      LFENCE();
    }
  }
  __syncthreads();  // the only block barrier

  // ---- ph2: attention, 2 heads, chunked (r12-proven) ----
  const f32x4 zero = (f32x4){0.f, 0.f, 0.f, 0.f};
  char* Pw = scr;
#pragma unroll
  for (int h = 0; h < 2; ++h) {
    const int dloc = h * 16 + l15;
    float psum = 0.f;
    f32x4 o = zero;
#pragma unroll
    for (int c = 0; c < 4; ++c) {
      f32x4 st[2];
#pragma unroll
      for (int hf = 0; hf < 2; ++hf) {
        const int krow = (c * 2 + hf) * 16 + l15;
        f16x8 ak = {0, 0, 0, 0, 0, 0, 0, 0};
        if (g < 2)
          ak = *(const f16x8*)(Kb + krow * 80 + (h * 16 + g * 8) * 2);
        st[hf] = __builtin_amdgcn_mfma_f32_16x16x32_f16(ak, bq[h], zero, 0, 0, 0);
      }
#pragma unroll
      for (int hf = 0; hf < 2; ++hf) {
        union { f16_t hh[4]; unsigned long long u; } pk;
#pragma unroll
        for (int r = 0; r < 4; ++r) {
          const int k = (c * 2 + hf) * 16 + g * 4 + r;
          const float e = __expf(st[hf][r] * 0.25f - 4.f);
          const float p = ((aw[k >> 5] >> (k & 31)) & 1u) ? e : 0.f;
          psum += p;   // row-sum for q = l15
          pk.hh[r] = (f16_t)p;
        }
        *(unsigned long long*)(Pw + l15 * 80 + hf * 32 + g * 8) = pk.u;
      }
      LFENCE();
      union { unsigned long long u[2]; f16x8 v; } pa2;
      pa2.u[0] = *(const unsigned long long*)(Pw + l15 * 80 + g * 16);
      pa2.u[1] = *(const unsigned long long*)(Pw + l15 * 80 + g * 16 + 8);
      LFENCE();
      f16x8 vb = *(const f16x8*)(Vtb + dloc * 256 + (((c * 32 + g * 8) * 2) ^ ((dloc & 7) << 4)));
      o = __builtin_amdgcn_mfma_f32_16x16x32_f16(pa2.v, vb, o, 0, 0, 0);
    }
    psum += __shfl_xor(psum, 16);
    psum += __shfl_xor(psum, 32);
    const float inv = 1.f / psum;  // for q = l15
#pragma unroll
    for (int r = 0; r < 4; ++r) {
      const float invq = __shfl(inv, g * 4 + r);  // for q = g*4+r (PV D-layout)
      const int row = rg * 16 + g * 4 + r;
      ATT[(size_t)bb * 16384 + row * 128 + colbase + h * 16 + l15] = (f16_t)(o[r] * invq);
    }
  }
}

// ---------------------------------------------------------------------------
// outgate3: straight-line out-proj + precomposed gate + blend (r6-proven math),
// re-tiled: wave = 16 rows x 32 cols (nt=2); 256 thr = 4 col-groups;
// grid 2048 (16 rows/block), zero LDS -> 8 blocks/CU = 32 waves/CU.
// ---------------------------------------------------------------------------
__global__ __launch_bounds__(256) void outgate3_kernel(
    const f16_t* __restrict__ AS, const f16_t* __restrict__ AC,
    const float* __restrict__ X, const f16_t* __restrict__ WT,
    const float* __restrict__ bos, const float* __restrict__ boc,
    const float* __restrict__ bgp, float* __restrict__ OUT)
{
  const int tid = threadIdx.x;
  const int wv = tid >> 6, ln = tid & 63, l15 = ln & 15, g = ln >> 4;
  const size_t arow = (size_t)blockIdx.x * 16 + l15;
  const f16_t* WoS = WT + 6 * 16384;
  const f16_t* WoC = WT + 7 * 16384;
  const f16_t* WgT = WT + 8 * 16384;   // [128][384]; k<128 = X part
  const f16_t* W2T = WT + 11 * 16384;
  const f16_t* W3T = WT + 12 * 16384;

  f32x4 accS[2], accC[2], accG[2];
#pragma unroll
  for (int nt = 0; nt < 2; ++nt) {
    accS[nt] = (f32x4){0.f, 0.f, 0.f, 0.f};
    accC[nt] = (f32x4){0.f, 0.f, 0.f, 0.f};
    accG[nt] = (f32x4){0.f, 0.f, 0.f, 0.f};
  }

#pragma unroll
  for (int kt = 0; kt < 4; ++kt) {
    const size_t ko = kt * 32 + g * 8;
    f16x8 aS = *(const f16x8*)(AS + arow * 128 + ko);
    f16x8 aC = *(const f16x8*)(AC + arow * 128 + ko);
    f16x8 aX = cvt8(X + arow * 128 + ko);
#pragma unroll
    for (int nt = 0; nt < 2; ++nt) {
      const size_t col = wv * 32 + nt * 16 + l15;
      f16x8 bS = *(const f16x8*)(WoS + col * 128 + ko);
      f16x8 bC = *(const f16x8*)(WoC + col * 128 + ko);
      f16x8 b2 = *(const f16x8*)(W2T + col * 128 + ko);
      f16x8 b3 = *(const f16x8*)(W3T + col * 128 + ko);
      f16x8 bX = *(const f16x8*)(WgT + col * 384 + ko);
      accS[nt] = __builtin_amdgcn_mfma_f32_16x16x32_f16(aS, bS, accS[nt], 0, 0, 0);
      accC[nt] = __builtin_amdgcn_mfma_f32_16x16x32_f16(aC, bC, accC[nt], 0, 0, 0);
      accG[nt] = __builtin_amdgcn_mfma_f32_16x16x32_f16(aX, bX, accG[nt], 0, 0, 0);
      accG[nt] = __builtin_amdgcn_mfma_f32_16x16x32_f16(aS, b2, accG[nt], 0, 0, 0);
      accG[nt] = __builtin_amdgcn_mfma_f32_16x16x32_f16(aC, b3, accG[nt], 0, 0, 0);
    }
  }

  const size_t orow0 = (size_t)blockIdx.x * 16 + g * 4;
#pragma unroll
  for (int nt = 0; nt < 2; ++nt) {
    const int col = wv * 32 + nt * 16 + l15;
    const float bS = bos[col], bC = boc[col], bG = bgp[col];
#pragma unroll
    for (int r = 0; r < 4; ++r) {
      const float os = accS[nt][r] + bS;
      const float oc = accC[nt][r] + bC;
      const float gv = 1.f / (1.f + __expf(-(accG[nt][r] + bG)));
      OUT[(orow0 + r) * 128 + col] = (1.f - gv) * os + gv * oc;
    }
  }
}

// ---------------------------------------------------------------------------
extern "C" void kernel_launch(void* const* d_in, const int* in_sizes, int n_in,
                              void* d_out, int out_size, void* d_ws, size_t ws_size,
                              hipStream_t stream)
{
  const float* x_self  = (const float*)d_in[0];
  const int*   adj     = (const int*)d_in[1];
  const int*   mask_s  = (const int*)d_in[2];
  const float* x_cross = (const float*)d_in[3];
  const int*   mask_c  = (const int*)d_in[4];
  const float* wq_s = (const float*)d_in[5];
  const float* bq_s = (const float*)d_in[6];
  const float* wk_s = (const float*)d_in[7];
  const float* bk_s = (const float*)d_in[8];
  const float* wv_s = (const float*)d_in[9];
  const float* bv_s = (const float*)d_in[10];
  const float* wo_s = (const float*)d_in[11];
  const float* bo_s = (const float*)d_in[12];
  const float* wq_c = (const float*)d_in[13];
  const float* bq_c = (const float*)d_in[14];
  const float* wk_c = (const float*)d_in[15];
  const float* bk_c = (const float*)d_in[16];
  const float* wv_c = (const float*)d_in[17];
  const float* bv_c = (const float*)d_in[18];
  const float* wo_c = (const float*)d_in[19];
  const float* bo_c = (const float*)d_in[20];
  const float* wg   = (const float*)d_in[21];
  const float* bg   = (const float*)d_in[22];
  float* out = (float*)d_out;

  // ws: 13 f16 weight slots + bg' (f32) + att_s/att_c (f16). ~17.2MB.
  const size_t SZ = (size_t)256 * 128 * 128;
  f16_t* WT  = (f16_t*)d_ws;
  float* bgp = (float*)(WT + 13 * 16384);
  f16_t* att_s = (f16_t*)(bgp + 128);
  f16_t* att_c = att_s + SZ;

  prep_kernel<<<14, 256, 0, stream>>>(wq_s, wk_s, wv_s, wq_c, wk_c, wv_c,
                                      wo_s, wo_c, wg, bo_s, bo_c, bg, WT, bgp);
  battn2_kernel<<<2048, 512, 0, stream>>>(x_self, x_cross, adj, mask_s, mask_c, WT,
                                          bq_s, bk_s, bv_s, bq_c, bk_c, bv_c,
                                          att_s, att_c);
  outgate3_kernel<<<2048, 256, 0, stream>>>(att_s, att_c, x_self, WT,
                                            bo_s, bo_c, bgp, out);
}

// Round 14
// 139.343 us; speedup vs baseline: 1.0603x; 1.0603x over previous
//
#include <hip/hip_runtime.h>
#include <hip/hip_bf16.h>

typedef _Float16 f16_t;
typedef __attribute__((ext_vector_type(8))) _Float16 f16x8;
typedef __attribute__((ext_vector_type(4))) float f32x4;

#define LFENCE() asm volatile("" ::: "memory")

__device__ __forceinline__ f16x8 cvt8(const float* p) {
  float4 v0 = *(const float4*)p;
  float4 v1 = *(const float4*)(p + 4);
  f16x8 a;
  a[0] = (f16_t)v0.x; a[1] = (f16_t)v0.y; a[2] = (f16_t)v0.z; a[3] = (f16_t)v0.w;
  a[4] = (f16_t)v1.x; a[5] = (f16_t)v1.y; a[6] = (f16_t)v1.z; a[7] = (f16_t)v1.w;
  return a;
}

// ---------------------------------------------------------------------------
// prep (verified r6-r13): blocks 0..10 transpose+f16 weights
//   slots 0..7 = {wq_s,wk_s,wv_s,wq_c,wk_c,wv_c,wo_s,wo_c}^T [col][k],
//   8..10 = WgT [128 col][384 k]. Blocks 11,12: W2'=(WoS@Wg2)^T, W3'=(WoC@Wg3)^T.
// Block 13: bg' = bg + bos@Wg2 + boc@Wg3.
// ---------------------------------------------------------------------------
__global__ __launch_bounds__(256) void prep_kernel(
    const float* wq_s, const float* wk_s, const float* wv_s,
    const float* wq_c, const float* wk_c, const float* wv_c,
    const float* wo_s, const float* wo_c, const float* wg,
    const float* bos, const float* boc, const float* bgin,
    f16_t* WT, float* bgp)
{
  const int b = blockIdx.x;
  const int tid = threadIdx.x;
  if (b < 11) {
    __shared__ float t[128][129];
    const float* src; f16_t* dst; int ostride;
    switch (b) {
      case 0: src = wq_s; break; case 1: src = wk_s; break;
      case 2: src = wv_s; break; case 3: src = wq_c; break;
      case 4: src = wk_c; break; case 5: src = wv_c; break;
      case 6: src = wo_s; break; case 7: src = wo_c; break;
      default: src = wg + (size_t)(b - 8) * 16384; break;
    }
    if (b < 8) { dst = WT + (size_t)b * 16384; ostride = 128; }
    else       { dst = WT + 8 * 16384 + (b - 8) * 128; ostride = 384; }
#pragma unroll
    for (int i = 0; i < 64; ++i) {
      const int idx = tid + i * 256;
      t[idx & 127][idx >> 7] = src[idx];
    }
    __syncthreads();
#pragma unroll
    for (int i = 0; i < 64; ++i) {
      const int idx = tid + i * 256;
      const int c = idx >> 7, r = idx & 127;
      dst[(size_t)c * ostride + r] = (f16_t)t[c][r];
    }
  } else if (b < 13) {
    const int matsel = b - 11;
    const float* wo = matsel ? wo_c : wo_s;
    const int joff = 128 + matsel * 128;
    f16_t* dst = WT + (size_t)(11 + matsel) * 16384;
    const int wv = tid >> 6, ln = tid & 63, l15 = ln & 15, g = ln >> 4;
    f32x4 acc[2][8];
#pragma unroll
    for (int mm = 0; mm < 2; ++mm)
#pragma unroll
      for (int nt = 0; nt < 8; ++nt) acc[mm][nt] = (f32x4){0.f, 0.f, 0.f, 0.f};
#pragma unroll
    for (int kt = 0; kt < 4; ++kt) {
      f16x8 a[2];
#pragma unroll
      for (int mm = 0; mm < 2; ++mm) {
        const int crow = wv * 32 + mm * 16 + l15;
#pragma unroll
        for (int jj = 0; jj < 8; ++jj)
          a[mm][jj] = (f16_t)wg[(size_t)(joff + kt * 32 + g * 8 + jj) * 128 + crow];
      }
#pragma unroll
      for (int nt = 0; nt < 8; ++nt) {
        f16x8 bf = cvt8(wo + (size_t)(nt * 16 + l15) * 128 + kt * 32 + g * 8);
        acc[0][nt] = __builtin_amdgcn_mfma_f32_16x16x32_f16(a[0], bf, acc[0][nt], 0, 0, 0);
        acc[1][nt] = __builtin_amdgcn_mfma_f32_16x16x32_f16(a[1], bf, acc[1][nt], 0, 0, 0);
      }
    }
#pragma unroll
    for (int mm = 0; mm < 2; ++mm)
#pragma unroll
      for (int nt = 0; nt < 8; ++nt)
#pragma unroll
        for (int r = 0; r < 4; ++r) {
          const int c = wv * 32 + mm * 16 + g * 4 + r;
          dst[(size_t)c * 128 + nt * 16 + l15] = (f16_t)acc[mm][nt][r];
        }
  } else {
    if (tid < 128) {
      float acc = bgin[tid];
      for (int j = 0; j < 128; ++j)
        acc += bos[j] * wg[(size_t)(128 + j) * 128 + tid] +
               boc[j] * wg[(size_t)(256 + j) * 128 + tid];
      bgp[tid] = acc;
    }
  }
}

// ---------------------------------------------------------------------------
// Branch+headgroup attention (r13 math verbatim, XCD-grouped block mapping):
// raw bid -> bb = (bid>>6)*8 + (bid&7); sub = (bid>>3)&7; self = !(sub&1);
// hg = sub>>1. HW maps wg->XCD by bid%8, so all 8 sub-blocks of a batch share
// one XCD's L2 -> x/adj duplicates served from L2 instead of HBM (r13: 107MB).
// 512 thr = 8 waves; LDS ~34KB -> 4 blocks/CU.
// ---------------------------------------------------------------------------
__global__ __launch_bounds__(512) void battn2_kernel(
    const float* __restrict__ Xs, const float* __restrict__ Xc,
    const int* __restrict__ adj, const int* __restrict__ mask_s,
    const int* __restrict__ mask_c, const f16_t* __restrict__ WT,
    const float* __restrict__ bq_s, const float* __restrict__ bk_s,
    const float* __restrict__ bv_s, const float* __restrict__ bq_c,
    const float* __restrict__ bk_c, const float* __restrict__ bv_c,
    f16_t* __restrict__ att_s, f16_t* __restrict__ att_c)
{
  __shared__ __align__(16) char Kb[128 * 80];
  __shared__ __align__(16) char Vtb[32 * 256];
  __shared__ __align__(16) char WS[8 * 1280];

  const int bid = blockIdx.x;
  const int bb = ((bid >> 6) << 3) + (bid & 7);  // batch; XCD = bb&7
  const int sub = (bid >> 3) & 7;
  const bool self = (sub & 1) == 0;
  const int hg = sub >> 1;            // head group 0..3 (2 heads each)
  const int colbase = hg * 32;
  const int tid = threadIdx.x;
  const int rg = tid >> 6, ln = tid & 63, l15 = ln & 15, g = ln >> 4;
  const int arow = rg * 16 + l15;
  char* scr = WS + rg * 1280;

  const f16_t* WQ = WT + (size_t)(self ? 0 : 3) * 16384;
  const f16_t* WK = WT + (size_t)(self ? 1 : 4) * 16384;
  const f16_t* WV = WT + (size_t)(self ? 2 : 5) * 16384;
  const float* bqv = self ? bq_s : bq_c;
  const float* bkv = self ? bk_s : bk_c;
  const float* bvv = self ? bv_s : bv_c;
  const float* XK  = self ? Xs : Xc;
  const int* mask  = self ? mask_s : mask_c;
  f16_t* ATT = self ? att_s : att_c;

  // masks via per-wave ballots (regs)
  unsigned mw[4];
  {
    unsigned long long m0 = __ballot(mask[bb * 128 + ln] != 0);
    unsigned long long m1 = __ballot(mask[bb * 128 + 64 + ln] != 0);
    mw[0] = (unsigned)m0; mw[1] = (unsigned)(m0 >> 32);
    mw[2] = (unsigned)m1; mw[3] = (unsigned)(m1 >> 32);
  }
  // adj bits -> regs (r12/r13-proven): lane ln loads word w=ln>>4 of row rg*16+(ln&15)
  unsigned aw[4];
  if (self) {
    const int row = rg * 16 + (ln & 15);
    const int w = ln >> 4;
    const int4* ap = (const int4*)(adj + ((size_t)bb * 128 + row) * 128 + w * 32);
    unsigned word = 0;
#pragma unroll
    for (int i = 0; i < 8; ++i) {
      int4 a = ap[i];
      word |= ((a.x != 0 ? 1u : 0u) | (a.y != 0 ? 2u : 0u) |
               (a.z != 0 ? 4u : 0u) | (a.w != 0 ? 8u : 0u)) << (i * 4);
    }
#pragma unroll
    for (int w2 = 0; w2 < 4; ++w2)
      aw[w2] = (unsigned)__shfl((int)word, w2 * 16 + l15) & mw[w2];
  } else {
#pragma unroll
    for (int w2 = 0; w2 < 4; ++w2) aw[w2] = mw[w2];
  }

  // ---- ph1: K (2 heads) -> Kb, V^T -> Vtb, Q -> bq[2] regs ----
  f16x8 bq[2];
  {
    f16x8 afrK[4];
#pragma unroll
    for (int kt = 0; kt < 4; ++kt)
      afrK[kt] = cvt8(XK + (size_t)bb * 16384 + arow * 128 + kt * 32 + g * 8);

    // K-proj: nt=0,1 -> Kb[row][lcol], stride 80B, no XOR
    {
      f32x4 acc[2];
      acc[0] = (f32x4){0.f, 0.f, 0.f, 0.f};
      acc[1] = (f32x4){0.f, 0.f, 0.f, 0.f};
#pragma unroll
      for (int nt = 0; nt < 2; ++nt)
#pragma unroll
        for (int kt = 0; kt < 4; ++kt) {
          f16x8 b = *(const f16x8*)(WK + (size_t)(colbase + nt * 16 + l15) * 128 + kt * 32 + g * 8);
          acc[nt] = __builtin_amdgcn_mfma_f32_16x16x32_f16(afrK[kt], b, acc[nt], 0, 0, 0);
        }
#pragma unroll
      for (int nt = 0; nt < 2; ++nt) {
        const int lcol = nt * 16 + l15;
        const float bv = bkv[colbase + lcol];
#pragma unroll
        for (int r = 0; r < 4; ++r) {
          const int row = rg * 16 + g * 4 + r;
          *(f16_t*)(Kb + row * 80 + lcol * 2) = (f16_t)(acc[nt][r] + bv);
        }
      }
    }
    // V-proj transposed: Vt[lcol][key], 256B stride, XOR (lcol&7)<<4
    {
      f32x4 acc[2];
      acc[0] = (f32x4){0.f, 0.f, 0.f, 0.f};
      acc[1] = (f32x4){0.f, 0.f, 0.f, 0.f};
#pragma unroll
      for (int nt = 0; nt < 2; ++nt)
#pragma unroll
        for (int kt = 0; kt < 4; ++kt) {
          f16x8 b = *(const f16x8*)(WV + (size_t)(colbase + nt * 16 + l15) * 128 + kt * 32 + g * 8);
          acc[nt] = __builtin_amdgcn_mfma_f32_16x16x32_f16(afrK[kt], b, acc[nt], 0, 0, 0);
        }
#pragma unroll
      for (int nt = 0; nt < 2; ++nt) {
        const int lcol = nt * 16 + l15;
        const float bv = bvv[colbase + lcol];
#pragma unroll
        for (int r = 0; r < 4; ++r) {
          const int row = rg * 16 + g * 4 + r;
          *(f16_t*)(Vtb + lcol * 256 + ((row * 2) ^ ((lcol & 7) << 4))) = (f16_t)(acc[nt][r] + bv);
        }
      }
    }
    // Q-proj -> scratch transpose -> bq[2] (r12/r13-proven mapping, stride 80)
    {
      f16x8 afrQ[4];
      if (self) {
#pragma unroll
        for (int kt = 0; kt < 4; ++kt) afrQ[kt] = afrK[kt];
      } else {
#pragma unroll
        for (int kt = 0; kt < 4; ++kt)
          afrQ[kt] = cvt8(Xs + (size_t)bb * 16384 + arow * 128 + kt * 32 + g * 8);
      }
      LFENCE();
      f32x4 acc[2];
      acc[0] = (f32x4){0.f, 0.f, 0.f, 0.f};
      acc[1] = (f32x4){0.f, 0.f, 0.f, 0.f};
#pragma unroll
      for (int nt = 0; nt < 2; ++nt)
#pragma unroll
        for (int kt = 0; kt < 4; ++kt) {
          f16x8 b = *(const f16x8*)(WQ + (size_t)(colbase + nt * 16 + l15) * 128 + kt * 32 + g * 8);
          acc[nt] = __builtin_amdgcn_mfma_f32_16x16x32_f16(afrQ[kt], b, acc[nt], 0, 0, 0);
        }
#pragma unroll
      for (int nt = 0; nt < 2; ++nt) {
        const int dloc = nt * 16 + l15;  // 0..31
        const float bv = bqv[colbase + dloc];
#pragma unroll
        for (int r = 0; r < 4; ++r) {
          const int qp = g * 4 + r;
          *(f16_t*)(scr + qp * 80 + dloc * 2) = (f16_t)(acc[nt][r] + bv);
        }
      }
      LFENCE();
#pragma unroll
      for (int h = 0; h < 2; ++h) {
        f16x8 z = {0, 0, 0, 0, 0, 0, 0, 0};
        bq[h] = (g < 2)
          ? *(const f16x8*)(scr + l15 * 80 + (h * 16 + g * 8) * 2)
          : z;
      }
      LFENCE();
    }
  }
  __syncthreads();  // the only block barrier

  // ---- ph2: attention, 2 heads, chunked (r12/r13-proven) ----
  const f32x4 zero = (f32x4){0.f, 0.f, 0.f, 0.f};
  char* Pw = scr;
#pragma unroll
  for (int h = 0; h < 2; ++h) {
    const int dloc = h * 16 + l15;
    float psum = 0.f;
    f32x4 o = zero;
#pragma unroll
    for (int c = 0; c < 4; ++c) {
      f32x4 st[2];
#pragma unroll
      for (int hf = 0; hf < 2; ++hf) {
        const int krow = (c * 2 + hf) * 16 + l15;
        f16x8 ak = {0, 0, 0, 0, 0, 0, 0, 0};
        if (g < 2)
          ak = *(const f16x8*)(Kb + krow * 80 + (h * 16 + g * 8) * 2);
        st[hf] = __builtin_amdgcn_mfma_f32_16x16x32_f16(ak, bq[h], zero, 0, 0, 0);
      }
#pragma unroll
      for (int hf = 0; hf < 2; ++hf) {
        union { f16_t hh[4]; unsigned long long u; } pk;
#pragma unroll
        for (int r = 0; r < 4; ++r) {
          const int k = (c * 2 + hf) * 16 + g * 4 + r;
          const float e = __expf(st[hf][r] * 0.25f - 4.f);
          const float p = ((aw[k >> 5] >> (k & 31)) & 1u) ? e : 0.f;
          psum += p;   // row-sum for q = l15
          pk.hh[r] = (f16_t)p;
        }
        *(unsigned long long*)(Pw + l15 * 80 + hf * 32 + g * 8) = pk.u;
      }
      LFENCE();
      union { unsigned long long u[2]; f16x8 v; } pa2;
      pa2.u[0] = *(const unsigned long long*)(Pw + l15 * 80 + g * 16);
      pa2.u[1] = *(const unsigned long long*)(Pw + l15 * 80 + g * 16 + 8);
      LFENCE();
      f16x8 vb = *(const f16x8*)(Vtb + dloc * 256 + (((c * 32 + g * 8) * 2) ^ ((dloc & 7) << 4)));
      o = __builtin_amdgcn_mfma_f32_16x16x32_f16(pa2.v, vb, o, 0, 0, 0);
    }
    psum += __shfl_xor(psum, 16);
    psum += __shfl_xor(psum, 32);
    const float inv = 1.f / psum;  // for q = l15
#pragma unroll
    for (int r = 0; r < 4; ++r) {
      const float invq = __shfl(inv, g * 4 + r);  // for q = g*4+r (PV D-layout)
      const int row = rg * 16 + g * 4 + r;
      ATT[(size_t)bb * 16384 + row * 128 + colbase + h * 16 + l15] = (f16_t)(o[r] * invq);
    }
  }
}

// ---------------------------------------------------------------------------
// outgate2 (verbatim r12, measured ~47us): straight-line out-proj +
// precomposed gate + blend. Grid 1024 x 256 thr; wave = 16 rows x 64 cols.
// ---------------------------------------------------------------------------
__global__ __launch_bounds__(256) void outgate2_kernel(
    const f16_t* __restrict__ AS, const f16_t* __restrict__ AC,
    const float* __restrict__ X, const f16_t* __restrict__ WT,
    const float* __restrict__ bos, const float* __restrict__ boc,
    const float* __restrict__ bgp, float* __restrict__ OUT)
{
  const int tid = threadIdx.x;
  const int wv = tid >> 6, ln = tid & 63, l15 = ln & 15, g = ln >> 4;
  const int rowgrp = wv & 1, colgrp = wv >> 1;
  const size_t arow = (size_t)blockIdx.x * 32 + rowgrp * 16 + l15;
  const f16_t* WoS = WT + 6 * 16384;
  const f16_t* WoC = WT + 7 * 16384;
  const f16_t* WgT = WT + 8 * 16384;   // [128][384]; k<128 = X part
  const f16_t* W2T = WT + 11 * 16384;
  const f16_t* W3T = WT + 12 * 16384;

  f32x4 accS[4], accC[4], accG[4];
#pragma unroll
  for (int nt = 0; nt < 4; ++nt) {
    accS[nt] = (f32x4){0.f, 0.f, 0.f, 0.f};
    accC[nt] = (f32x4){0.f, 0.f, 0.f, 0.f};
    accG[nt] = (f32x4){0.f, 0.f, 0.f, 0.f};
  }

#pragma unroll
  for (int kt = 0; kt < 4; ++kt) {
    const size_t ko = kt * 32 + g * 8;
    f16x8 aS = *(const f16x8*)(AS + arow * 128 + ko);
    f16x8 aC = *(const f16x8*)(AC + arow * 128 + ko);
    f16x8 aX = cvt8(X + arow * 128 + ko);
#pragma unroll
    for (int nt = 0; nt < 4; ++nt) {
      const size_t col = colgrp * 64 + nt * 16 + l15;
      f16x8 bS = *(const f16x8*)(WoS + col * 128 + ko);
      f16x8 bC = *(const f16x8*)(WoC + col * 128 + ko);
      f16x8 b2 = *(const f16x8*)(W2T + col * 128 + ko);
      f16x8 b3 = *(const f16x8*)(W3T + col * 128 + ko);
      f16x8 bX = *(const f16x8*)(WgT + col * 384 + ko);
      accS[nt] = __builtin_amdgcn_mfma_f32_16x16x32_f16(aS, bS, accS[nt], 0, 0, 0);
      accC[nt] = __builtin_amdgcn_mfma_f32_16x16x32_f16(aC, bC, accC[nt], 0, 0, 0);
      accG[nt] = __builtin_amdgcn_mfma_f32_16x16x32_f16(aX, bX, accG[nt], 0, 0, 0);
      accG[nt] = __builtin_amdgcn_mfma_f32_16x16x32_f16(aS, b2, accG[nt], 0, 0, 0);
      accG[nt] = __builtin_amdgcn_mfma_f32_16x16x32_f16(aC, b3, accG[nt], 0, 0, 0);
    }
  }

  const size_t orow0 = (size_t)blockIdx.x * 32 + rowgrp * 16 + g * 4;
#pragma unroll
  for (int nt = 0; nt < 4; ++nt) {
    const int col = colgrp * 64 + nt * 16 + l15;
    const float bS = bos[col], bC = boc[col], bG = bgp[col];
#pragma unroll
    for (int r = 0; r < 4; ++r) {
      const float os = accS[nt][r] + bS;
      const float oc = accC[nt][r] + bC;
      const float gv = 1.f / (1.f + __expf(-(accG[nt][r] + bG)));
      OUT[(orow0 + r) * 128 + col] = (1.f - gv) * os + gv * oc;
    }
  }
}

// ---------------------------------------------------------------------------
extern "C" void kernel_launch(void* const* d_in, const int* in_sizes, int n_in,
                              void* d_out, int out_size, void* d_ws, size_t ws_size,
                              hipStream_t stream)
{
  const float* x_self  = (const float*)d_in[0];
  const int*   adj     = (const int*)d_in[1];
  const int*   mask_s  = (const int*)d_in[2];
  const float* x_cross = (const float*)d_in[3];
  const int*   mask_c  = (const int*)d_in[4];
  const float* wq_s = (const float*)d_in[5];
  const float* bq_s = (const float*)d_in[6];
  const float* wk_s = (const float*)d_in[7];
  const float* bk_s = (const float*)d_in[8];
  const float* wv_s = (const float*)d_in[9];
  const float* bv_s = (const float*)d_in[10];
  const float* wo_s = (const float*)d_in[11];
  const float* bo_s = (const float*)d_in[12];
  const float* wq_c = (const float*)d_in[13];
  const float* bq_c = (const float*)d_in[14];
  const float* wk_c = (const float*)d_in[15];
  const float* bk_c = (const float*)d_in[16];
  const float* wv_c = (const float*)d_in[17];
  const float* bv_c = (const float*)d_in[18];
  const float* wo_c = (const float*)d_in[19];
  const float* bo_c = (const float*)d_in[20];
  const float* wg   = (const float*)d_in[21];
  const float* bg   = (const float*)d_in[22];
  float* out = (float*)d_out;

  // ws: 13 f16 weight slots + bg' (f32) + att_s/att_c (f16). ~17.2MB.
  const size_t SZ = (size_t)256 * 128 * 128;
  f16_t* WT  = (f16_t*)d_ws;
  float* bgp = (float*)(WT + 13 * 16384);
  f16_t* att_s = (f16_t*)(bgp + 128);
  f16_t* att_c = att_s + SZ;

  prep_kernel<<<14, 256, 0, stream>>>(wq_s, wk_s, wv_s, wq_c, wk_c, wv_c,
                                      wo_s, wo_c, wg, bo_s, bo_c, bg, WT, bgp);
  battn2_kernel<<<2048, 512, 0, stream>>>(x_self, x_cross, adj, mask_s, mask_c, WT,
                                          bq_s, bk_s, bv_s, bq_c, bk_c, bv_c,
                                          att_s, att_c);
  outgate2_kernel<<<1024, 256, 0, stream>>>(att_s, att_c, x_self, WT,
                                            bo_s, bo_c, bgp, out);
}